// Round 7
// baseline (223.497 us; speedup 1.0000x reference)
//
#include <hip/hip_runtime.h>
#include <math.h>

#define BN_ 8
#define CIN 256
#define COUT 256
#define HH 64
#define WW 64
#define HW 4096
#define KK 9
#define OC 18
#define EPS 1e-5f
#define NTOT (BN_ * COUT * HW)

// ws layout (float units):
//   off_ws: [B][18][HW]                 = 589824 floats
//   wTb:    bf16 [72][4][256][8] shorts = 294912 floats (main GEMM A image)
//   wob:    bf16 [72][4][32][8] shorts  = 36864 floats  (offset-conv A image)
//   stats:  [2][COUT]                   = 512 floats
//   xt:     bf16 [B][32][HW][8] shorts  = 4194304 floats (g8-planar x: pixel stride 16B)
#define OFF_WS 0
#define WTB_WS 589824
#define WOB_WS 884736
#define ST_WS  921600
#define XT_WS  922112

typedef float f32x4 __attribute__((ext_vector_type(4)));
typedef float f32x2 __attribute__((ext_vector_type(2)));
typedef short s16x8 __attribute__((ext_vector_type(8)));
typedef unsigned int u32x4 __attribute__((ext_vector_type(4)));

__device__ __forceinline__ unsigned short f2bf(float f) {
  unsigned int u = __float_as_uint(f);
  unsigned int r = (u + 0x7fffu + ((u >> 16) & 1u)) >> 16;  // RNE
  return (unsigned short)r;
}
__device__ __forceinline__ float bf2f(short s) {
  return __uint_as_float(((unsigned int)(unsigned short)s) << 16);
}

// ---------------- Kernel T: transpose x -> xt[b][g8][p][8] bf16 ----------------
__global__ __launch_bounds__(256) void xpose_kernel(
    const float* __restrict__ x, unsigned short* __restrict__ xt) {
  __shared__ float s[64][65];
  const int t = threadIdx.x;
  const int p0 = blockIdx.x * 64;
  const int c0 = blockIdx.y * 64;
  const int b  = blockIdx.z;
  const float* xb = x + ((size_t)b * CIN + c0) * HW + p0;
#pragma unroll
  for (int pass = 0; pass < 4; ++pass) {
    int cr = pass * 16 + (t >> 4);
    int ps = (t & 15) * 4;
    float4 v = *(const float4*)(xb + (size_t)cr * HW + ps);
    s[ps + 0][cr] = v.x; s[ps + 1][cr] = v.y; s[ps + 2][cr] = v.z; s[ps + 3][cr] = v.w;
  }
  __syncthreads();
  unsigned short* xo = xt + (size_t)b * 32 * HW * 8;
#pragma unroll
  for (int r = 0; r < 2; ++r) {
    int flat = r * 256 + t;
    int pr = flat >> 3, sub = flat & 7;
    int g8 = (c0 >> 3) + sub;
    s16x8 v;
#pragma unroll
    for (int j = 0; j < 8; ++j) v[j] = (short)f2bf(s[pr][sub * 8 + j]);
    *(s16x8*)(xo + ((size_t)g8 * HW + p0 + pr) * 8) = v;
  }
}

// ---------------- Kernel P: pack w_off + w, zero stats (merged prep) ----------------
__global__ __launch_bounds__(256) void prep_kernel(
    const float* __restrict__ w_off, const float* __restrict__ w,
    unsigned short* __restrict__ wob, unsigned short* __restrict__ wTb,
    float* __restrict__ stats) {
  const int kb = blockIdx.x;          // 0..71
  const int kk = kb >> 3;
  const int c0 = (kb & 7) << 5;
  const int t = threadIdx.x;
  if (kb == 71) { stats[t] = 0.f; stats[256 + t] = 0.f; }
  // w_off pack (M=32 pad)
#pragma unroll
  for (int r = 0; r < 4; ++r) {
    int e = r * 256 + t;              // g*256 + m*8 + j
    int g = e >> 8, m = (e >> 3) & 31, j = e & 7;
    int c = c0 + g * 8 + j;
    unsigned short v = 0;
    if (m < OC) v = f2bf(w_off[((size_t)m * CIN + c) * 9 + kk]);
    wob[(size_t)kb * 1024 + e] = v;
  }
  // w pack (k-major)
#pragma unroll
  for (int g = 0; g < 4; ++g)
#pragma unroll
    for (int j = 0; j < 8; ++j) {
      int c = c0 + g * 8 + j;
      wTb[(((size_t)kb * 4 + g) * 256 + t) * 8 + j] =
          f2bf(w[((size_t)t * CIN + c) * 9 + kk]);
    }
}

// ---------------- Kernel A: offset conv as MFMA GEMM, K-split across waves ----------------
__global__ __launch_bounds__(256) void offset_kernel(
    const unsigned short* __restrict__ xt, const unsigned short* __restrict__ wob,
    const float* __restrict__ b_off, float* __restrict__ off_ws) {
  __shared__ __align__(16) char smem[32768];
  const int t = threadIdx.x;
  const int lane = t & 63;
  const int wv = t >> 6;
  const int b = blockIdx.x & 7;
  const int h = blockIdx.x >> 3;
  const unsigned short* xtb = xt + (size_t)b * 32 * HW * 8;
  const int fr = lane & 15, fq = lane >> 4;
  unsigned short* sb = (unsigned short*)smem + wv * 2048;
  float* red = (float*)smem;

  f32x4 acc[2][4] = {};

  for (int s = 0; s < 18; ++s) {
    const int ki = wv * 18 + s;
    const int kk = ki >> 3, cc0 = (ki & 7) << 5;
    const int ky = kk / 3 - 1, kx = kk % 3 - 1;
    const int y = h + ky;
    const bool yok = (y >= 0) && (y < HH);
    const int xcol = lane + kx;
    const bool ok = yok && (xcol >= 0) && (xcol < WW);
    const int pix = y * WW + xcol;

    s16x8 af[2];
    const unsigned short* ap = wob + (size_t)ki * 1024;
#pragma unroll
    for (int i = 0; i < 2; ++i)
      af[i] = *(const s16x8*)&ap[(fq * 32 + i * 16 + fr) * 8];

#pragma unroll
    for (int g = 0; g < 4; ++g) {
      s16x8 v = {0, 0, 0, 0, 0, 0, 0, 0};
      if (ok)
        __builtin_memcpy(&v, (const char*)xtb + ((((size_t)(cc0 >> 3) + g) << 16)) + (size_t)pix * 16, 16);
      *(s16x8*)&sb[(g * 64 + lane) * 8] = v;
    }
    __builtin_amdgcn_s_waitcnt(0);

    s16x8 bf[4];
#pragma unroll
    for (int jn = 0; jn < 4; ++jn)
      bf[jn] = *(const s16x8*)&sb[(fq * 64 + jn * 16 + fr) * 8];
#pragma unroll
    for (int i = 0; i < 2; ++i)
#pragma unroll
      for (int jn = 0; jn < 4; ++jn)
        acc[i][jn] = __builtin_amdgcn_mfma_f32_16x16x32_bf16(af[i], bf[jn], acc[i][jn], 0, 0, 0);
  }

  __syncthreads();
#pragma unroll
  for (int i = 0; i < 2; ++i)
#pragma unroll
    for (int jn = 0; jn < 4; ++jn)
#pragma unroll
      for (int rg = 0; rg < 4; ++rg)
        red[wv * 2048 + (i * 16 + fq * 4 + rg) * 64 + jn * 16 + fr] = acc[i][jn][rg];
  __syncthreads();

  const int m = t >> 3;
  const int pq = (t & 7) * 8;
  float4 v0 = make_float4(0.f, 0.f, 0.f, 0.f), v1 = v0;
#pragma unroll
  for (int w = 0; w < 4; ++w) {
    float4 a = *(float4*)&red[w * 2048 + m * 64 + pq];
    float4 c = *(float4*)&red[w * 2048 + m * 64 + pq + 4];
    v0.x += a.x; v0.y += a.y; v0.z += a.z; v0.w += a.w;
    v1.x += c.x; v1.y += c.y; v1.z += c.z; v1.w += c.w;
  }
  if (m < OC) {
    float bo = b_off[m];
    v0.x += bo; v0.y += bo; v0.z += bo; v0.w += bo;
    v1.x += bo; v1.y += bo; v1.z += bo; v1.w += bo;
    float* op = off_ws + ((size_t)b * OC + m) * HW + h * WW + pq;
    *(float4*)op = v0;
    *(float4*)(op + 4) = v1;
  }
}

// ---------------- Kernel B: producer/consumer split gather-GEMM + fused stats ----------------
// 512 threads = 8 waves. Waves 0-3 = CONSUMERS: pure MFMA, M=64/wave
// (32 MFMA/iter from s_b[cur]). Waves 4-7 = PRODUCERS: offsets + gather +
// packed-fma combine into s_b[cur^1] (2 octet-slots/thread, one cofs set).
// Same barrier count in both roles (wave-uniform branch, barriers inside each
// branch); between two barriers P builds tile I+1 WHILE C consumes tile I, so
// the former phase-sum (mem -> MFMA -> combine) now overlaps across waves.
// Roles live in disjoint code regions so register sets don't union:
// C ~110 VGPR (acc 64 + af 32), P ~45 -> fits launch_bounds(512,4) cap 128.
__global__ __launch_bounds__(512, 4) void gemm_kernel(
    const unsigned short* __restrict__ xt, const unsigned short* __restrict__ wTb,
    const float* __restrict__ off_ws, const float* __restrict__ bias,
    float* __restrict__ out, float* __restrict__ stats) {
  __shared__ unsigned short s_b[2][4096];   // [buf][oct(8)][px(64)][8]
  const int t = threadIdx.x;
  const int lane = t & 63;
  const int wv = t >> 6;               // 0..7
  const int b = blockIdx.x & 7;
  const int h = blockIdx.x >> 3;
  const int p0 = h * 64;
  const int fr = lane & 15, fq = lane >> 4;
  const unsigned short* xtb = xt + (size_t)b * 32 * HW * 8;

  if (wv < 4) {
    // ================= CONSUMER (waves 0-3): MFMA only =================
    f32x4 acc[4][4] = {};
    s16x8 af[2][4];                    // [ks][m-frag], M=64/wave

    auto load_af = [&](int iter) {
#pragma unroll
      for (int ks = 0; ks < 2; ++ks) {
        const unsigned short* ap =
            wTb + (((size_t)(iter * 2 + ks) * 4 + fq) * 256 + wv * 64 + fr) * 8;
#pragma unroll
        for (int i = 0; i < 4; ++i)
          af[ks][i] = *(const s16x8*)(ap + (size_t)i * 16 * 8);
      }
    };

    load_af(0);
    asm volatile("s_waitcnt lgkmcnt(0)" ::: "memory");
    __builtin_amdgcn_s_barrier();

    for (int I = 0; I < 36; ++I) {
      const int cur = I & 1;
      __builtin_amdgcn_s_setprio(1);
#pragma unroll
      for (int ks = 0; ks < 2; ++ks)
#pragma unroll
        for (int jj = 0; jj < 4; ++jj) {
          s16x8 bfr = *(const s16x8*)&s_b[cur][((ks * 4 + fq) * 64 + jj * 16 + fr) * 8];
#pragma unroll
          for (int ii = 0; ii < 4; ++ii)
            acc[ii][jj] = __builtin_amdgcn_mfma_f32_16x16x32_bf16(
                af[ks][ii], bfr, acc[ii][jj], 0, 0, 0);
        }
      __builtin_amdgcn_s_setprio(0);
      if (I + 1 < 36) load_af(I + 1);  // WAR on af: after last MFMA issue
      asm volatile("s_waitcnt lgkmcnt(0)" ::: "memory");
      __builtin_amdgcn_s_barrier();
    }

    // epilogue: + bias, store, fused per-channel sum/sumsq (consumers only)
#pragma unroll
    for (int i = 0; i < 4; ++i) {
#pragma unroll
      for (int rg = 0; rg < 4; ++rg) {
        int o = wv * 64 + i * 16 + fq * 4 + rg;
        float bv = bias[o];
        float* op = out + ((size_t)(b * COUT + o)) * HW + p0 + fr;
        float s = 0.f, s2 = 0.f;
#pragma unroll
        for (int j = 0; j < 4; ++j) {
          float val = acc[i][j][rg] + bv;
          op[j * 16] = val;
          s += val; s2 += val * val;
        }
#pragma unroll
        for (int m2 = 1; m2 < 16; m2 <<= 1) {
          s += __shfl_xor(s, m2);
          s2 += __shfl_xor(s2, m2);
        }
        if (fr == 0) {
          atomicAdd(&stats[o], s);
          atomicAdd(&stats[COUT + o], s2);
        }
      }
    }
  } else {
    // ================= PRODUCER (waves 4-7): gather + combine =================
    const int col = lane;              // pixel column
    const int octp = wv & 3;           // octet-pair: octets {2*octp, 2*octp+1}
    const float* offp = off_ws + (size_t)b * OC * HW + p0 + col;

    int cofs[4];                       // corner byte offsets: (cy*WW+cx)*16
    f32x2 qw2[4];                      // bilinear weights (broadcast pairs)
    s16x8 g[2][4];                     // [octet-slot][corner]

    auto calc = [&](int kk, float dy, float dx) {
      float py = (float)(kk / 3 - 1 + h) + dy;
      float pxx = (float)(kk % 3 - 1 + col) + dx;
      float y0f = floorf(py), x0f = floorf(pxx);
      float fy = py - y0f, fx = pxx - x0f;
      int y0 = (int)y0f, x0 = (int)x0f;
      int y1 = y0 + 1, x1 = x0 + 1;
      bool vy0 = (y0 >= 0) && (y0 < HH), vy1 = (y1 >= 0) && (y1 < HH);
      bool vx0 = (x0 >= 0) && (x0 < WW), vx1 = (x1 >= 0) && (x1 < WW);
      int cy0 = min(max(y0, 0), HH - 1), cy1 = min(max(y1, 0), HH - 1);
      int cx0 = min(max(x0, 0), WW - 1), cx1 = min(max(x1, 0), WW - 1);
      float q0 = (vy0 && vx0) ? (1.f - fy) * (1.f - fx) : 0.f;
      float q1 = (vy0 && vx1) ? (1.f - fy) * fx : 0.f;
      float q2 = (vy1 && vx0) ? fy * (1.f - fx) : 0.f;
      float q3 = (vy1 && vx1) ? fy * fx : 0.f;
      cofs[0] = (cy0 * WW + cx0) * 16;  qw2[0][0] = q0; qw2[0][1] = q0;
      cofs[1] = (cy0 * WW + cx1) * 16;  qw2[1][0] = q1; qw2[1][1] = q1;
      cofs[2] = (cy1 * WW + cx0) * 16;  qw2[2][0] = q2; qw2[2][1] = q2;
      cofs[3] = (cy1 * WW + cx1) * 16;  qw2[3][0] = q3; qw2[3][1] = q3;
    };

    auto gather = [&](int chunk64) {
      // planes g8 = chunk64*8 + octp*2 + {0,1}; plane = 64KB
      const char* bp0 = (const char*)xtb + (((size_t)(chunk64 * 8 + octp * 2)) << 16);
#pragma unroll
      for (int k = 0; k < 4; ++k) {
        __builtin_memcpy(&g[0][k], bp0 + cofs[k], 16);
        __builtin_memcpy(&g[1][k], bp0 + (1 << 16) + cofs[k], 16);
      }
    };

    auto combine_write = [&](int buf) {
#pragma unroll
      for (int slot = 0; slot < 2; ++slot) {
        u32x4 vout;
#pragma unroll
        for (int jp = 0; jp < 4; ++jp) {
          f32x2 a = {0.f, 0.f};
#pragma unroll
          for (int k = 0; k < 4; ++k) {
            unsigned int pr = ((const unsigned int*)&g[slot][k])[jp];
            f32x2 xv;
            xv[0] = __uint_as_float(pr << 16);
            xv[1] = __uint_as_float(pr & 0xffff0000u);
            a = __builtin_elementwise_fma(qw2[k], xv, a);
          }
          unsigned int packed;
          asm("v_cvt_pk_bf16_f32 %0, %1, %2" : "=v"(packed) : "v"(a[0]), "v"(a[1]));
          vout[jp] = packed;
        }
        *(u32x4*)&s_b[buf][((octp * 2 + slot) * 64 + col) * 8] = vout;
      }
    };

    float dyp, dxp;
    {
      float dy0 = offp[0];
      float dx0 = offp[HW];
      calc(0, dy0, dx0);
      dyp = offp[2 * HW];
      dxp = offp[3 * HW];
      gather(0);
      combine_write(0);
    }
    asm volatile("s_waitcnt lgkmcnt(0)" ::: "memory");
    __builtin_amdgcn_s_barrier();

    for (int I = 0; I < 36; ++I) {
      const int nx1 = I + 1;
      if (nx1 < 36) {
        if ((nx1 & 3) == 0) {
          const int kkc = nx1 >> 2;
          calc(kkc, dyp, dxp);
          const int kkn = kkc + 1;
          if (kkn < 9) {
            dyp = offp[(size_t)(2 * kkn) * HW];
            dxp = offp[(size_t)(2 * kkn + 1) * HW];
          }
        }
        gather(nx1 & 3);
        combine_write((I & 1) ^ 1);
      }
      asm volatile("s_waitcnt lgkmcnt(0)" ::: "memory");
      __builtin_amdgcn_s_barrier();
    }
  }
}

// ---------------- Kernel D: normalize + ReLU in-place ----------------
__global__ __launch_bounds__(256) void bn_kernel(
    float* __restrict__ out, const float* __restrict__ stats,
    const float* __restrict__ gamma, const float* __restrict__ beta) {
  int i4 = (blockIdx.x * 256 + threadIdx.x) * 4;
  int o = (i4 >> 12) & (COUT - 1);
  const float inv_n = 1.f / (float)(BN_ * HW);
  float mean = stats[o] * inv_n;
  float var = stats[COUT + o] * inv_n - mean * mean;
  float sc = gamma[o] * rsqrtf(var + EPS);
  float sh = beta[o] - mean * sc;
  float4 v = *(float4*)(out + i4);
  v.x = fmaxf(fmaf(v.x, sc, sh), 0.f);
  v.y = fmaxf(fmaf(v.y, sc, sh), 0.f);
  v.z = fmaxf(fmaf(v.z, sc, sh), 0.f);
  v.w = fmaxf(fmaf(v.w, sc, sh), 0.f);
  *(float4*)(out + i4) = v;
}

extern "C" void kernel_launch(void* const* d_in, const int* in_sizes, int n_in,
                              void* d_out, int out_size, void* d_ws, size_t ws_size,
                              hipStream_t stream) {
  const float* x     = (const float*)d_in[0];
  const float* w_off = (const float*)d_in[1];
  const float* b_off = (const float*)d_in[2];
  const float* w     = (const float*)d_in[3];
  const float* bias  = (const float*)d_in[4];
  const float* gamma = (const float*)d_in[5];
  const float* beta  = (const float*)d_in[6];
  float* out = (float*)d_out;
  float* ws = (float*)d_ws;
  float* off_ws = ws + OFF_WS;
  unsigned short* wTb = (unsigned short*)(ws + WTB_WS);
  unsigned short* wob = (unsigned short*)(ws + WOB_WS);
  float* stats = ws + ST_WS;
  unsigned short* xt = (unsigned short*)(ws + XT_WS);

  xpose_kernel<<<dim3(64, 4, 8), 256, 0, stream>>>(x, xt);
  prep_kernel<<<72, 256, 0, stream>>>(w_off, w, wob, wTb, stats);
  offset_kernel<<<512, 256, 0, stream>>>(xt, wob, b_off, off_ws);
  gemm_kernel<<<512, 512, 0, stream>>>(xt, wTb, off_ws, bias, out, stats);
  bn_kernel<<<NTOT / 1024, 256, 0, stream>>>(out, stats, gamma, beta);
}